// Round 3
// baseline (72.029 us; speedup 1.0000x reference)
//
#include <hip/hip_runtime.h>

// ConvDeepSet: B=16, N=512, M=1024, CIN=7 (C=8 with ones-channel), COUT=64.
// out[b,m,o] = sum_c f(b,m,c) * W[o,c] + bias[o]
//   f[...,0]   = density  = sum_n exp(k_0 * d)
//   f[...,c>0] = (sum_n ctx[n,c] * exp(k_c * d)) / (density + 1e-8)
//   d = (context_in[b,n] - target_in[b,m])^2 ; k_c = -0.5 * exp(-2*sigma_c)
//
// LDS record per n: [ci, x1..x7]  (ci in the ones-channel slot; density
// accumulates w directly). Uniform-sigma fast path: one exp per (n,m) pair.

namespace {
constexpr int Bc    = 16;
constexpr int Nc    = 512;
constexpr int Mc    = 1024;
constexpr int CINc  = 7;
constexpr int Cc    = 8;      // 1 + CIN
constexpr int CP    = 9;      // padded channel stride for reduce buffer
constexpr int COUTc = 64;
constexpr int TM    = 16;     // m-values per block
constexpr int NCH   = 32;     // n-chunks per block
constexpr int NPC   = Nc / NCH;        // 16 n per chunk
constexpr int THREADS = TM * NCH;      // 512 threads = 8 waves
constexpr int NWAVES  = THREADS / 64;  // 8
constexpr float LOG2E = 1.4426950408889634f;
}

__global__ __launch_bounds__(THREADS, 8) void convdeepset_kernel(
    const float* __restrict__ context_in,   // (B,N,1)
    const float* __restrict__ context_out,  // (B,N,CIN)
    const float* __restrict__ target_in,    // (B,M,1)
    const float* __restrict__ sigma,        // (C,)
    const float* __restrict__ W,            // (COUT,C)
    const float* __restrict__ bias,         // (COUT,)
    float* __restrict__ out)                // (B,M,COUT)
{
    __shared__ float s_ctx[Nc * Cc];           // [n][0]=ci, [n][1+c]=context_out
    __shared__ float s_red[NWAVES][TM][CP];    // per-wave partials (padded)
    __shared__ float s_tot[TM][Cc];
    __shared__ float s_f[TM][Cc];
    __shared__ float s_Wt[Cc][COUTc];
    __shared__ float s_bias[COUTc];
    __shared__ float s_k2[Cc];                 // k_c * log2(e)

    const int t   = threadIdx.x;
    const int blk = blockIdx.x;
    const int b   = blk / (Mc / TM);
    const int m0  = (blk % (Mc / TM)) * TM;

    // ---- stage constants ----
    if (t < COUTc) s_bias[t] = bias[t];
    if (t < Cc) {
        float s = sigma[t];
        float inv_sc2 = __builtin_amdgcn_exp2f(-2.0f * s * LOG2E);  // exp(-2*sigma)
        s_k2[t] = -0.5f * inv_sc2 * LOG2E;
    }
    {   // W: 512 elements == THREADS
        int o = t / Cc, c = t % Cc;
        s_Wt[c][o] = W[t];
    }
    // ---- stage per-batch context ----
    s_ctx[t * Cc] = context_in[b * Nc + t];    // THREADS == Nc
    #pragma unroll
    for (int r = 0; r < (Nc * CINc) / THREADS; r++) {   // 7 iters, exact
        int e = r * THREADS + t;
        int n = e / CINc, c = e % CINc;
        s_ctx[n * Cc + 1 + c] = context_out[b * Nc * CINc + e];
    }
    __syncthreads();

    const int mi  = t & (TM - 1);   // m within tile  (lane bits 0..3)
    const int ncq = t >> 4;         // n-chunk 0..31  (lane bits 4,5 + wave id)
    const float ti = target_in[b * Mc + m0 + mi];

    const float k0 = s_k2[0];
    bool uniform = true;
    #pragma unroll
    for (int c = 1; c < Cc; c++) uniform = uniform && (s_k2[c] == k0);

    float acc[Cc];
    #pragma unroll
    for (int c = 0; c < Cc; c++) acc[c] = 0.0f;

    const int nbase = ncq * NPC;
    if (uniform) {
        // Uniform length-scales (actual bench data): ONE exp per pair.
        #pragma unroll 4
        for (int j = 0; j < NPC; j++) {
            const float4* p = (const float4*)&s_ctx[(nbase + j) * Cc];
            const float4 c0 = p[0], c1 = p[1];      // c0.x = ci
            const float diff = c0.x - ti;
            const float w = __builtin_amdgcn_exp2f((k0 * diff) * diff);
            acc[0] += w;
            acc[1] += c0.y * w; acc[2] += c0.z * w; acc[3] += c0.w * w;
            acc[4] += c1.x * w; acc[5] += c1.y * w; acc[6] += c1.z * w; acc[7] += c1.w * w;
        }
    } else {
        // General path (unused by bench data): per-channel exponent; k from LDS broadcast.
        #pragma unroll 2
        for (int j = 0; j < NPC; j++) {
            const float4* p = (const float4*)&s_ctx[(nbase + j) * Cc];
            const float4 c0 = p[0], c1 = p[1];
            const float diff = c0.x - ti;
            const float d = diff * diff;
            acc[0] +=        __builtin_amdgcn_exp2f(s_k2[0] * d);
            acc[1] += c0.y * __builtin_amdgcn_exp2f(s_k2[1] * d);
            acc[2] += c0.z * __builtin_amdgcn_exp2f(s_k2[2] * d);
            acc[3] += c0.w * __builtin_amdgcn_exp2f(s_k2[3] * d);
            acc[4] += c1.x * __builtin_amdgcn_exp2f(s_k2[4] * d);
            acc[5] += c1.y * __builtin_amdgcn_exp2f(s_k2[5] * d);
            acc[6] += c1.z * __builtin_amdgcn_exp2f(s_k2[6] * d);
            acc[7] += c1.w * __builtin_amdgcn_exp2f(s_k2[7] * d);
        }
    }

    // ---- in-wave reduce over the 4 n-chunks a wave spans (lane bits 4,5) ----
    #pragma unroll
    for (int c = 0; c < Cc; c++) {
        acc[c] += __shfl_xor(acc[c], 16);
        acc[c] += __shfl_xor(acc[c], 32);
    }
    {
        const int lane = t & 63;
        const int w    = t >> 6;        // wave id 0..7
        if (lane < TM) {                // lane == mi here
            #pragma unroll
            for (int c = 0; c < Cc; c++) s_red[w][lane][c] = acc[c];
        }
    }
    __syncthreads();

    // ---- reduce over 8 waves: thread u<128 owns (mi=u/8, c=u%8) ----
    if (t < TM * Cc) {
        const int rmi = t >> 3;
        const int rc  = t & 7;
        float tot = 0.0f;
        #pragma unroll
        for (int k = 0; k < NWAVES; k++) tot += s_red[k][rmi][rc];
        s_tot[rmi][rc] = tot;
    }
    __syncthreads();
    if (t < TM * Cc) {
        const int rmi = t >> 3;
        const int rc  = t & 7;
        const float tot  = s_tot[rmi][rc];
        const float dens = s_tot[rmi][0];
        s_f[rmi][rc] = (rc == 0) ? tot : tot / (dens + 1e-8f);
    }
    __syncthreads();

    // ---- epilogue: (TM x C) @ (C x COUT) + bias, coalesced stores ----
    const long long obase = (long long)(b * Mc + m0) * COUTc;
    #pragma unroll
    for (int r = 0; r < (TM * COUTc) / THREADS; r++) {   // 2 iters
        const int flat = r * THREADS + t;
        const int o    = flat & (COUTc - 1);  // = lane -> coalesced, conflict-free
        const int rmi  = flat / COUTc;        // wave-uniform -> LDS broadcast
        float v = s_bias[o];
        #pragma unroll
        for (int c = 0; c < Cc; c++) v += s_f[rmi][c] * s_Wt[c][o];
        out[obase + flat] = v;
    }
}

extern "C" void kernel_launch(void* const* d_in, const int* in_sizes, int n_in,
                              void* d_out, int out_size, void* d_ws, size_t ws_size,
                              hipStream_t stream) {
    const float* context_in  = (const float*)d_in[0];
    const float* context_out = (const float*)d_in[1];
    const float* target_in   = (const float*)d_in[2];
    const float* sigma       = (const float*)d_in[3];
    const float* W           = (const float*)d_in[4];
    const float* bias        = (const float*)d_in[5];
    float* out = (float*)d_out;

    const int grid = Bc * (Mc / TM);  // 1024 blocks x 512 threads -> 4 blocks/CU
    convdeepset_kernel<<<grid, THREADS, 0, stream>>>(
        context_in, context_out, target_in, sigma, W, bias, out);
}